// Round 1
// baseline (7644.875 us; speedup 1.0000x reference)
//
#include <hip/hip_runtime.h>

// RegressiveAutoEncoder: B=2048, T=512, F=8, H=128.
// Encoder LSTM (512 steps) -> autoregressive decoder LSTM + Dense(relu) (512 steps).
// Strategy: persistent block per 8 batch rows (256 blocks, 256 threads), full
// time loop inside the kernel. fp32 everywhere (correctness baseline).
// Thread t: hc = t&127 (H column), gp = t>>7 (gate pair 0->(i,f), 1->(g,o)).
// GEMM: each thread accumulates z for 8 rows x 2 unique gate columns so U is
// read from L2 exactly once per block per step (no duplication). z staged in
// LDS; cell update re-partitions as (hc, 4 rows) per thread with c in regs.

namespace {
constexpr int TSTEPS = 512;
constexpr int NF = 8;
constexpr int NH = 128;
constexpr int G4 = 4 * NH;   // 512
constexpr int BT = 8;        // batch rows per block
constexpr int NTH = 256;
constexpr int HPAD = 12;     // padded inner dim of transposed h (16B-aligned rows, conflict-light writes)

struct Smem {
  float hT[NH][HPAD];   // h transposed: hT[k][row]
  float xy[BT][NF];     // current input vector (x_t for encoder, y_{t-1} for decoder)
  float w[NF][G4];      // W_enc or W_dec
  float b[G4];          // b_enc or b_dec
  float z[BT][G4];      // pre-activation staging
  float wout[NH][NF];
  float bout[NF];
};

__device__ __forceinline__ float sigm(float x) { return 1.0f / (1.0f + __expf(-x)); }
// tanh via exp; saturates correctly at +-inf without NaN.
__device__ __forceinline__ float tanh_(float x) { return 1.0f - 2.0f / (__expf(2.0f * x) + 1.0f); }

__device__ __forceinline__ void gemm_z(Smem& s, const float* __restrict__ U, int hc, int gp) {
  const int g0 = 2 * gp;
  float acc[BT][2];
  const float b0 = s.b[g0 * NH + hc];
  const float b1 = s.b[(g0 + 1) * NH + hc];
#pragma unroll
  for (int r = 0; r < BT; ++r) { acc[r][0] = b0; acc[r][1] = b1; }
  // x (or y) @ W contribution
#pragma unroll
  for (int ft = 0; ft < NF; ++ft) {
    const float w0 = s.w[ft][g0 * NH + hc];
    const float w1 = s.w[ft][(g0 + 1) * NH + hc];
#pragma unroll
    for (int r = 0; r < BT; ++r) {
      const float xv = s.xy[r][ft];
      acc[r][0] = fmaf(xv, w0, acc[r][0]);
      acc[r][1] = fmaf(xv, w1, acc[r][1]);
    }
  }
  // h @ U contribution; U streamed from L2 (coalesced: consecutive hc -> consecutive addr)
  const float* Ub = U + g0 * NH + hc;
#pragma unroll 8
  for (int k = 0; k < NH; ++k) {
    const float u0 = Ub[k * G4];
    const float u1 = Ub[k * G4 + NH];
    const float4 hA = *(const float4*)&s.hT[k][0];
    const float4 hB = *(const float4*)&s.hT[k][4];
    acc[0][0] = fmaf(hA.x, u0, acc[0][0]); acc[0][1] = fmaf(hA.x, u1, acc[0][1]);
    acc[1][0] = fmaf(hA.y, u0, acc[1][0]); acc[1][1] = fmaf(hA.y, u1, acc[1][1]);
    acc[2][0] = fmaf(hA.z, u0, acc[2][0]); acc[2][1] = fmaf(hA.z, u1, acc[2][1]);
    acc[3][0] = fmaf(hA.w, u0, acc[3][0]); acc[3][1] = fmaf(hA.w, u1, acc[3][1]);
    acc[4][0] = fmaf(hB.x, u0, acc[4][0]); acc[4][1] = fmaf(hB.x, u1, acc[4][1]);
    acc[5][0] = fmaf(hB.y, u0, acc[5][0]); acc[5][1] = fmaf(hB.y, u1, acc[5][1]);
    acc[6][0] = fmaf(hB.z, u0, acc[6][0]); acc[6][1] = fmaf(hB.z, u1, acc[6][1]);
    acc[7][0] = fmaf(hB.w, u0, acc[7][0]); acc[7][1] = fmaf(hB.w, u1, acc[7][1]);
  }
#pragma unroll
  for (int r = 0; r < BT; ++r) {
    s.z[r][g0 * NH + hc] = acc[r][0];
    s.z[r][(g0 + 1) * NH + hc] = acc[r][1];
  }
}

// Cell update: thread owns (column hq, rows rq*4..rq*4+3); c kept in registers
// with an identical (thread -> cells) mapping in encoder and decoder phases.
__device__ __forceinline__ void cell_update(Smem& s, int hq, int rq, float c[4]) {
#pragma unroll
  for (int rr = 0; rr < 4; ++rr) {
    const int r = rq * 4 + rr;
    const float iv = sigm(s.z[r][hq]);
    const float fv = sigm(s.z[r][NH + hq]);
    const float gv = tanh_(s.z[r][2 * NH + hq]);
    const float ov = sigm(s.z[r][3 * NH + hq]);
    c[rr] = fv * c[rr] + iv * gv;
    s.hT[hq][r] = ov * tanh_(c[rr]);
  }
}

__global__ __launch_bounds__(NTH, 1)
void rae_fused(const float* __restrict__ x,
               const float* __restrict__ Wenc, const float* __restrict__ Uenc,
               const float* __restrict__ benc,
               const float* __restrict__ Wdec, const float* __restrict__ Udec,
               const float* __restrict__ bdec,
               const float* __restrict__ Wout, const float* __restrict__ bout,
               float* __restrict__ out)
{
  __shared__ Smem s;
  const int tid = threadIdx.x;
  const int hc = tid & (NH - 1);
  const int gp = tid >> 7;                 // 0 or 1
  const long gb = (long)blockIdx.x * BT;   // global batch row base

  for (int i = tid; i < NF * G4; i += NTH) (&s.w[0][0])[i] = Wenc[i];
  for (int i = tid; i < G4; i += NTH) s.b[i] = benc[i];
  for (int i = tid; i < NH * NF; i += NTH) (&s.wout[0][0])[i] = Wout[i];
  if (tid < NF) s.bout[tid] = bout[tid];
  for (int i = tid; i < NH * HPAD; i += NTH) (&s.hT[0][0])[i] = 0.0f;
  if (tid < BT * NF) {
    const int r = tid >> 3, ft = tid & 7;
    s.xy[r][ft] = x[((gb + r) * TSTEPS + 0) * NF + ft];
  }
  float c[4] = {0.f, 0.f, 0.f, 0.f};
  __syncthreads();

  // ---------------- encoder ----------------
  for (int t = 0; t < TSTEPS; ++t) {
    gemm_z(s, Uenc, hc, gp);
    __syncthreads();                       // z visible; all hT/xy reads done
    cell_update(s, hc, gp, c);             // writes hT
    if (t + 1 < TSTEPS && tid < BT * NF) { // stage x_{t+1}
      const int r = tid >> 3, ft = tid & 7;
      s.xy[r][ft] = x[((gb + r) * TSTEPS + (t + 1)) * NF + ft];
    }
    __syncthreads();
  }

  // switch weights to decoder; y0 = x[:, T-1, :]
  for (int i = tid; i < NF * G4; i += NTH) (&s.w[0][0])[i] = Wdec[i];
  for (int i = tid; i < G4; i += NTH) s.b[i] = bdec[i];
  if (tid < BT * NF) {
    const int r = tid >> 3, ft = tid & 7;
    s.xy[r][ft] = x[((gb + r) * TSTEPS + (TSTEPS - 1)) * NF + ft];
  }
  __syncthreads();

  // ---------------- decoder ----------------
  for (int t = 0; t < TSTEPS; ++t) {
    gemm_z(s, Udec, hc, gp);
    __syncthreads();
    cell_update(s, hc, gp, c);
    __syncthreads();                       // hT visible for y computation
    if (tid < BT * NF) {
      const int r = tid >> 3, ft = tid & 7;
      float a = s.bout[ft];
#pragma unroll 16
      for (int k = 0; k < NH; ++k) a = fmaf(s.hT[k][r], s.wout[k][ft], a);
      a = fmaxf(a, 0.0f);
      s.xy[r][ft] = a;                     // feedback
      out[((gb + r) * TSTEPS + t) * NF + ft] = a;
    }
    __syncthreads();                       // xy visible before next gemm
  }
}
} // namespace

extern "C" void kernel_launch(void* const* d_in, const int* in_sizes, int n_in,
                              void* d_out, int out_size, void* d_ws, size_t ws_size,
                              hipStream_t stream) {
  const float* x    = (const float*)d_in[0];
  const float* Wenc = (const float*)d_in[1];
  const float* Uenc = (const float*)d_in[2];
  const float* benc = (const float*)d_in[3];
  const float* Wdec = (const float*)d_in[4];
  const float* Udec = (const float*)d_in[5];
  const float* bdec = (const float*)d_in[6];
  const float* Wout = (const float*)d_in[7];
  const float* bout = (const float*)d_in[8];
  float* out = (float*)d_out;

  const int Bsz = in_sizes[0] / (TSTEPS * NF);   // 2048
  const int nblocks = Bsz / BT;                  // 256
  rae_fused<<<dim3(nblocks), dim3(NTH), 0, stream>>>(
      x, Wenc, Uenc, benc, Wdec, Udec, bdec, Wout, bout, out);
}

// Round 2
// 2583.121 us; speedup vs baseline: 2.9595x; 2.9595x over previous
//
#include <hip/hip_runtime.h>

// RegressiveAutoEncoder B=2048,T=512,F=8,H=128 — MFMA version.
// 256 blocks x 512 threads; block owns 8 batch rows for all 1024 timesteps.
// z[16x512] = [h|x][16x160] @ [U;W][160x512] via mfma_f32_16x16x32_bf16,
// split-bf16 3-term (hi@Bhi + hi@Blo + lo@Bhi) for ~fp32 accuracy.
// B-fragments (U,W split) are register-resident per wave (wave w -> cols w*64..+63
// == exactly one half-gate, so gate g lives in waves 2g,2g+1).
// C/D layout: col=lane&15, row=(lane>>4)*4+reg. A: A[m=lane&15][k=(lane>>4)*8+j].
// B: B[k=(lane>>4)*8+j][n=lane&15] (B^T-symmetric to A).

namespace {

typedef __attribute__((ext_vector_type(8))) short bf16x8;
typedef __attribute__((ext_vector_type(4))) float f32x4;

constexpr int T = 512, F = 8, H = 128, G4 = 512, BT = 8, NTH = 512;
constexpr int HS = 136;  // ushort stride for hhi/hlo rows (272B = 17*16 -> b128-aligned)
constexpr int ZS = 129;  // float stride for z (odd -> 2-way-free bank pattern)
constexpr int FS = 132;  // float stride for hf/woutT (528B, 16B-aligned rows)

struct __align__(16) Smem {
  unsigned short hhi[BT][HS];   // h split-high, A-operand layout (row-major, k contiguous)
  unsigned short hlo[BT][HS];   // h split-low
  unsigned short xhi[BT][F];    // current input (x_t or y_{t-1}) split-high
  unsigned short xlo[BT][F];
  float hf[BT][FS];             // h fp32 (for decoder Dense)
  float z[4][BT][ZS];           // gate pre-activations [gate][row][col]
  float woutT[F][FS];           // W_out transposed [f][k]
  float bout[F];
};

__device__ __forceinline__ float sigm(float x) { return 1.0f / (1.0f + __expf(-x)); }
__device__ __forceinline__ float tanh_(float x) { return 1.0f - 2.0f / (__expf(2.0f * x) + 1.0f); }

// Truncating hi/lo bf16 split: hi+lo represents v to ~2^-16 relative.
__device__ __forceinline__ void split2(float v, unsigned& hi, unsigned& lo) {
  unsigned b = __float_as_uint(v);
  hi = b >> 16;
  float vh = __uint_as_float(b & 0xFFFF0000u);
  lo = __float_as_uint(v - vh) >> 16;
}

__global__ __launch_bounds__(NTH, 2)
void rae_mfma(const float* __restrict__ x,
              const float* __restrict__ Wenc, const float* __restrict__ Uenc, const float* __restrict__ benc,
              const float* __restrict__ Wdec, const float* __restrict__ Udec, const float* __restrict__ bdec,
              const float* __restrict__ Wout, const float* __restrict__ boutg,
              float* __restrict__ out)
{
  __shared__ Smem s;
  const int tid = threadIdx.x;
  const int lane = tid & 63;
  const int w = tid >> 6;          // wave id: owns gate-cols [w*64, w*64+64)
  const int q = lane >> 4;         // k-quad
  const int mm = lane & 15;        // A row / B col-in-tile
  const bool act = mm < BT;        // A rows 8..15 are zero padding
  const long gb = (long)blockIdx.x * BT;
  const int ncol0 = w * 64 + mm;

  // ---- setup: zero h state, stage x_0, stage W_out^T ----
  for (int i = tid; i < BT * HS; i += NTH) { (&s.hhi[0][0])[i] = 0; (&s.hlo[0][0])[i] = 0; }
  for (int i = tid; i < BT * FS; i += NTH) (&s.hf[0][0])[i] = 0.0f;
  for (int i = tid; i < H * F; i += NTH) s.woutT[i & 7][i >> 3] = Wout[i];
  if (tid < F) s.bout[tid] = boutg[tid];
  if (tid < 64) {
    unsigned hb, lb; split2(x[(gb + (tid >> 3)) * (long)(T * F) + (tid & 7)], hb, lb);
    s.xhi[tid >> 3][tid & 7] = (unsigned short)hb;
    s.xlo[tid >> 3][tid & 7] = (unsigned short)lb;
  }
  float c0 = 0.0f, c1 = 0.0f;  // cell state: lane j of wave r owns cells (r, j), (r, j+64)
  __syncthreads();

  bf16x8 Bhi[5][4], Blo[5][4];  // register-resident U|W fragments (160 VGPRs)
  float brg[4];

  for (int ph = 0; ph < 2; ++ph) {
    const float* U  = ph ? Udec : Uenc;
    const float* W  = ph ? Wdec : Wenc;
    const float* bi = ph ? bdec : benc;

    // ---- B-fragment preload (once per phase): k 0..127 = U, k 128..135 = W, rest 0 ----
#pragma unroll
    for (int kt = 0; kt < 5; ++kt) {
#pragma unroll
      for (int tl = 0; tl < 4; ++tl) {
        bf16x8 hi, lo;
#pragma unroll
        for (int j = 0; j < 8; ++j) {
          float u;
          if (kt < 4) u = U[(kt * 32 + q * 8 + j) * G4 + ncol0 + tl * 16];
          else        u = (q == 0) ? W[j * G4 + ncol0 + tl * 16] : 0.0f;
          unsigned hb, lb; split2(u, hb, lb);
          hi[j] = (short)hb; lo[j] = (short)lb;
        }
        Bhi[kt][tl] = hi; Blo[kt][tl] = lo;
      }
    }
#pragma unroll
    for (int tl = 0; tl < 4; ++tl) brg[tl] = bi[ncol0 + tl * 16];

    for (int t = 0; t < T; ++t) {
      // prefetch next encoder input (latency hidden under MFMA phase)
      float xnext = 0.0f;
      if (ph == 0 && tid < 64 && t + 1 < T)
        xnext = x[(gb + (tid >> 3)) * (long)(T * F) + (t + 1) * F + (tid & 7)];

      // ---- A fragments: [h | x] split hi/lo ----
      bf16x8 Ahi[5], Alo[5];
#pragma unroll
      for (int kt = 0; kt < 4; ++kt) {
        bf16x8 ah, al;
        if (act) {
          ah = *(const bf16x8*)&s.hhi[mm][kt * 32 + q * 8];
          al = *(const bf16x8*)&s.hlo[mm][kt * 32 + q * 8];
        } else {
#pragma unroll
          for (int j = 0; j < 8; ++j) { ah[j] = 0; al[j] = 0; }
        }
        Ahi[kt] = ah; Alo[kt] = al;
      }
      {
        bf16x8 ah, al;
        if (act && q == 0) {
          ah = *(const bf16x8*)&s.xhi[mm][0];
          al = *(const bf16x8*)&s.xlo[mm][0];
        } else {
#pragma unroll
          for (int j = 0; j < 8; ++j) { ah[j] = 0; al[j] = 0; }
        }
        Ahi[4] = ah; Alo[4] = al;
      }

      // ---- MFMA: acc = bias; 3 passes x 5 ksteps x 4 tiles ----
      f32x4 acc[4];
#pragma unroll
      for (int tl = 0; tl < 4; ++tl) acc[tl] = f32x4{brg[tl], brg[tl], brg[tl], brg[tl]};
#pragma unroll
      for (int kt = 0; kt < 5; ++kt)
#pragma unroll
        for (int tl = 0; tl < 4; ++tl)
          acc[tl] = __builtin_amdgcn_mfma_f32_16x16x32_bf16(Ahi[kt], Bhi[kt][tl], acc[tl], 0, 0, 0);
#pragma unroll
      for (int kt = 0; kt < 5; ++kt)
#pragma unroll
        for (int tl = 0; tl < 4; ++tl)
          acc[tl] = __builtin_amdgcn_mfma_f32_16x16x32_bf16(Ahi[kt], Blo[kt][tl], acc[tl], 0, 0, 0);
#pragma unroll
      for (int kt = 0; kt < 5; ++kt)
#pragma unroll
        for (int tl = 0; tl < 4; ++tl)
          acc[tl] = __builtin_amdgcn_mfma_f32_16x16x32_bf16(Alo[kt], Bhi[kt][tl], acc[tl], 0, 0, 0);

      // ---- stage z (real rows 0..7 live in lanes 0..31) ----
      if (lane < 32) {
        const int row0 = (lane >> 4) * 4;
        const int cg = ((w & 1) << 6) + mm;
        const int g = w >> 1;
#pragma unroll
        for (int tl = 0; tl < 4; ++tl)
#pragma unroll
          for (int p = 0; p < 4; ++p)
            s.z[g][row0 + p][cg + tl * 16] = acc[tl][p];
      }
      __syncthreads();

      // ---- cell update: wave r=w owns batch row w; lane j owns cols j, j+64 ----
      {
        const int r = w, j = lane;
        float zi0 = s.z[0][r][j],      zf0 = s.z[1][r][j],      zg0 = s.z[2][r][j],      zo0 = s.z[3][r][j];
        float zi1 = s.z[0][r][j + 64], zf1 = s.z[1][r][j + 64], zg1 = s.z[2][r][j + 64], zo1 = s.z[3][r][j + 64];
        c0 = sigm(zf0) * c0 + sigm(zi0) * tanh_(zg0);
        c1 = sigm(zf1) * c1 + sigm(zi1) * tanh_(zg1);
        float h0 = sigm(zo0) * tanh_(c0);
        float h1 = sigm(zo1) * tanh_(c1);
        s.hf[r][j] = h0; s.hf[r][j + 64] = h1;
        // split + pack pairs via shfl so all LDS writes are dword-wide (no same-word b16 races)
        unsigned h0h, h0l, h1h, h1l;
        split2(h0, h0h, h0l); split2(h1, h1h, h1l);
        unsigned P0 = h0h | (h0l << 16), P1 = h1h | (h1l << 16);
        unsigned X0 = __shfl_xor(P0, 1, 64);
        unsigned X1 = __shfl_xor(P1, 1, 64);
        if ((j & 1) == 0) {           // cols (j, j+1)
          *(unsigned*)&s.hhi[r][j] = h0h | (X0 << 16);
          *(unsigned*)&s.hlo[r][j] = h0l | (X0 & 0xFFFF0000u);
        } else {                      // cols (j+63, j+64)
          *(unsigned*)&s.hhi[r][j + 63] = (X1 & 0xFFFFu) | (h1h << 16);
          *(unsigned*)&s.hlo[r][j + 63] = (X1 >> 16) | (h1l << 16);
        }
      }

      if (ph == 0) {
        if (tid < 64 && t + 1 < T) {  // stage x_{t+1}
          unsigned hb, lb; split2(xnext, hb, lb);
          s.xhi[tid >> 3][tid & 7] = (unsigned short)hb;
          s.xlo[tid >> 3][tid & 7] = (unsigned short)lb;
        }
        __syncthreads();
      } else {
        __syncthreads();
        // ---- y = relu(h @ Wout + bout); lane = f*8 + q, wave = batch row ----
        const int r = w, f = (lane >> 3) & 7, qq = lane & 7;
        const float4* hv = (const float4*)&s.hf[r][qq * 16];
        const float4* wv = (const float4*)&s.woutT[f][qq * 16];
        float a = 0.0f;
#pragma unroll
        for (int i = 0; i < 4; ++i) {
          float4 hx = hv[i], wx = wv[i];
          a = fmaf(hx.x, wx.x, a); a = fmaf(hx.y, wx.y, a);
          a = fmaf(hx.z, wx.z, a); a = fmaf(hx.w, wx.w, a);
        }
        a += __shfl_xor(a, 1, 64);
        a += __shfl_xor(a, 2, 64);
        a += __shfl_xor(a, 4, 64);
        if (qq == 0) {
          float y = fmaxf(a + s.bout[f], 0.0f);
          out[((gb + r) * T + t) * F + f] = y;
          unsigned hb, lb; split2(y, hb, lb);
          s.xhi[r][f] = (unsigned short)hb;   // feedback for next step
          s.xlo[r][f] = (unsigned short)lb;
        }
        __syncthreads();
      }
    }
  }
}

} // namespace

extern "C" void kernel_launch(void* const* d_in, const int* in_sizes, int n_in,
                              void* d_out, int out_size, void* d_ws, size_t ws_size,
                              hipStream_t stream) {
  const float* x    = (const float*)d_in[0];
  const float* Wenc = (const float*)d_in[1];
  const float* Uenc = (const float*)d_in[2];
  const float* benc = (const float*)d_in[3];
  const float* Wdec = (const float*)d_in[4];
  const float* Udec = (const float*)d_in[5];
  const float* bdec = (const float*)d_in[6];
  const float* Wout = (const float*)d_in[7];
  const float* bout = (const float*)d_in[8];
  float* out = (float*)d_out;

  const int Bsz = in_sizes[0] / (T * F);  // 2048
  const int nblocks = Bsz / BT;           // 256
  rae_mfma<<<dim3(nblocks), dim3(NTH), 0, stream>>>(
      x, Wenc, Uenc, benc, Wdec, Udec, bdec, Wout, bout, out);
}

// Round 3
// 1931.870 us; speedup vs baseline: 3.9572x; 1.3371x over previous
//
#include <hip/hip_runtime.h>

// RegressiveAutoEncoder B=2048,T=512,F=8,H=128 — MFMA v3.
// 256 blocks x 512 threads (8 waves); block owns 8 batch rows, 1024 steps.
// z[16x512] = [h|x|xlo][16x160] @ B[160x512] via mfma_f32_16x16x32_bf16.
// 2-term split: pass1 A@B1 (hi), pass2 A@B2 (lo). h = rtn-bf16 (single term);
// U = hi+lo (2 terms); x/y = 3-term via spare k-slots 136..143 (x_lo@W_hi).
// A rows 8..15 are permanently-zero LDS rows (no zero-fill VALU, results land
// in discarded lanes>=32 accs). B-fragments register-resident (160 VGPR).
// Decoder: Dense reads own wave's hf row (no extra barrier) -> 2 barriers/step.

namespace {

typedef __attribute__((ext_vector_type(8))) short bf16x8;
typedef __attribute__((ext_vector_type(4))) float f32x4;

constexpr int T = 512, F = 8, H = 128, G4 = 512, NTH = 512;
constexpr int HS = 136;  // ushort stride, hhi rows (272B, 16B-aligned)
constexpr int XS = 32;   // ushort stride, xpad rows (64B): [hi 0..7 | lo 8..15 | zeros]
constexpr int ZS = 129;  // float stride, z
constexpr int FS = 132;  // float stride, hf/woutT (528B, 16B-aligned)

struct __align__(16) Smem {
  unsigned short hhi[16][HS];  // h as rtn-bf16, A-layout; rows 8..15 stay zero
  unsigned short xpad[16][XS]; // current input: hi | lo | zeros; rows 8..15 zero
  float hf[8][FS];             // h fp32 (decoder Dense)
  float z[4][8][ZS];           // gate pre-activations [gate][row][col]
  float woutT[F][FS];          // W_out^T [f][k]
  float bout[F];
};

__device__ __forceinline__ float sigm(float x) { return 1.0f / (1.0f + __expf(-x)); }
__device__ __forceinline__ float tanh_(float x) { return 1.0f - 2.0f / (__expf(2.0f * x) + 1.0f); }

__device__ __forceinline__ unsigned short bf_rtn(float v) {
  unsigned u = __float_as_uint(v);
  return (unsigned short)((u + 0x7FFFu + ((u >> 16) & 1u)) >> 16);
}
// exact-ish split: hi = truncate(v), lo = rtn(v - hi); hi+lo ~ v to 2^-17
__device__ __forceinline__ void split_tr(float v, unsigned short& hi, unsigned short& lo) {
  unsigned u = __float_as_uint(v);
  hi = (unsigned short)(u >> 16);
  lo = bf_rtn(v - __uint_as_float(u & 0xFFFF0000u));
}

__global__ __launch_bounds__(NTH, 2)
void rae_mfma2(const float* __restrict__ x,
               const float* __restrict__ Wenc, const float* __restrict__ Uenc, const float* __restrict__ benc,
               const float* __restrict__ Wdec, const float* __restrict__ Udec, const float* __restrict__ bdec,
               const float* __restrict__ Wout, const float* __restrict__ boutg,
               float* __restrict__ out)
{
  __shared__ Smem s;
  const int tid = threadIdx.x;
  const int lane = tid & 63;
  const int w = tid >> 6;          // wave: owns gate-cols [w*64, w*64+64) and batch row w
  const int q = lane >> 4;         // k-quad
  const int mm = lane & 15;        // A row / B col-in-tile
  const long gb = (long)blockIdx.x * 8;

  // ---- one-time setup ----
  for (int i = tid; i < 16 * HS; i += NTH) (&s.hhi[0][0])[i] = 0;
  for (int i = tid; i < 16 * XS; i += NTH) (&s.xpad[0][0])[i] = 0;
  for (int i = tid; i < 8 * FS; i += NTH) (&s.hf[0][0])[i] = 0.0f;
  for (int i = tid; i < H * F; i += NTH) s.woutT[i & 7][i >> 3] = Wout[i];
  if (tid < F) s.bout[tid] = boutg[tid];
  if (tid < 64) {
    unsigned short hb, lb;
    split_tr(x[(gb + (tid >> 3)) * (long)(T * F) + (tid & 7)], hb, lb);
    s.xpad[tid >> 3][tid & 7] = hb;
    s.xpad[tid >> 3][(tid & 7) + 8] = lb;
  }
  float c0 = 0.0f, c1 = 0.0f;  // cell state: wave w row w, lane j cols (j, j+64)
  __syncthreads();

  bf16x8 B1[5][4], B2[5][4];
  float brg[4];

  for (int ph = 0; ph < 2; ++ph) {
    const float* U  = ph ? Udec : Uenc;
    const float* W  = ph ? Wdec : Wenc;
    const float* bi = ph ? bdec : benc;

    // ---- B-fragment preload (global only; no LDS hazard) ----
#pragma unroll
    for (int kt = 0; kt < 5; ++kt) {
#pragma unroll
      for (int tl = 0; tl < 4; ++tl) {
        const int col = w * 64 + tl * 16 + mm;
        bf16x8 b1, b2;
#pragma unroll
        for (int j = 0; j < 8; ++j) {
          unsigned short hb = 0, lb = 0;
          if (kt < 4) {
            split_tr(U[(kt * 32 + q * 8 + j) * G4 + col], hb, lb);
          } else {
            const int kk = q * 8 + j;
            if (kk < 8) split_tr(W[kk * G4 + col], hb, lb);          // x_hi slots
            else if (kk < 16) { unsigned short t2; split_tr(W[(kk - 8) * G4 + col], hb, t2); lb = 0; } // x_lo@W_hi
          }
          b1[j] = (short)hb; b2[j] = (short)lb;
        }
        B1[kt][tl] = b1; B2[kt][tl] = b2;
      }
    }
#pragma unroll
    for (int tl = 0; tl < 4; ++tl) brg[tl] = bi[w * 64 + tl * 16 + mm];
    // (decoder y0 = x[:,T-1,:] is already in xpad from the encoder's last stage)

    for (int t = 0; t < T; ++t) {
      float xnext = 0.0f;
      if (ph == 0 && tid < 64 && t + 1 < T)
        xnext = x[(gb + (tid >> 3)) * (long)(T * F) + (t + 1) * F + (tid & 7)];

      // ---- A fragments (all lanes; rows 8..15 read zeros) ----
      bf16x8 A[5];
#pragma unroll
      for (int kt = 0; kt < 4; ++kt)
        A[kt] = *(const bf16x8*)&s.hhi[mm][kt * 32 + q * 8];
      A[4] = *(const bf16x8*)&s.xpad[mm][q * 8];

      // ---- MFMA: 2 passes x 5 ksteps x 4 tiles ----
      f32x4 acc[4];
#pragma unroll
      for (int tl = 0; tl < 4; ++tl) acc[tl] = f32x4{brg[tl], brg[tl], brg[tl], brg[tl]};
#pragma unroll
      for (int kt = 0; kt < 5; ++kt)
#pragma unroll
        for (int tl = 0; tl < 4; ++tl)
          acc[tl] = __builtin_amdgcn_mfma_f32_16x16x32_bf16(A[kt], B1[kt][tl], acc[tl], 0, 0, 0);
#pragma unroll
      for (int kt = 0; kt < 5; ++kt)
#pragma unroll
        for (int tl = 0; tl < 4; ++tl)
          acc[tl] = __builtin_amdgcn_mfma_f32_16x16x32_bf16(A[kt], B2[kt][tl], acc[tl], 0, 0, 0);

      // ---- stage z (rows 0..7 live in lanes 0..31) ----
      if (lane < 32) {
        const int row0 = (lane >> 4) * 4;
        const int cg = ((w & 1) << 6) + mm;
        const int g = w >> 1;
#pragma unroll
        for (int tl = 0; tl < 4; ++tl)
#pragma unroll
          for (int p = 0; p < 4; ++p)
            s.z[g][row0 + p][cg + tl * 16] = acc[tl][p];
      }
      __syncthreads();   // z ready; all hhi/xpad reads complete

      // ---- cell update: wave w owns row w; lane j owns cols j, j+64 ----
      {
        const int r = w, j = lane;
        float zi0 = s.z[0][r][j],      zf0 = s.z[1][r][j],      zg0 = s.z[2][r][j],      zo0 = s.z[3][r][j];
        float zi1 = s.z[0][r][j + 64], zf1 = s.z[1][r][j + 64], zg1 = s.z[2][r][j + 64], zo1 = s.z[3][r][j + 64];
        c0 = sigm(zf0) * c0 + sigm(zi0) * tanh_(zg0);
        c1 = sigm(zf1) * c1 + sigm(zi1) * tanh_(zg1);
        const float h0 = sigm(zo0) * tanh_(c0);
        const float h1 = sigm(zo1) * tanh_(c1);
        s.hhi[r][j] = bf_rtn(h0);         // disjoint b16 stores: race-free, 2-way free
        s.hhi[r][j + 64] = bf_rtn(h1);
        if (ph == 1) { s.hf[r][j] = h0; s.hf[r][j + 64] = h1; }
      }

      if (ph == 0) {
        if (tid < 64 && t + 1 < T) {
          unsigned short hb, lb; split_tr(xnext, hb, lb);
          s.xpad[tid >> 3][tid & 7] = hb;
          s.xpad[tid >> 3][(tid & 7) + 8] = lb;
        }
      } else {
        // ---- Dense: wave w reads its OWN freshly written hf row (intra-wave
        // LDS RAW -> compiler waitcnt, no barrier). lane = f*8 + qq. ----
        const int f = lane >> 3, qq = lane & 7;
        const float4* hv = (const float4*)&s.hf[w][qq * 16];
        const float4* wv = (const float4*)&s.woutT[f][qq * 16];
        float a = 0.0f;
#pragma unroll
        for (int i = 0; i < 4; ++i) {
          float4 hx = hv[i], wx = wv[i];
          a = fmaf(hx.x, wx.x, a); a = fmaf(hx.y, wx.y, a);
          a = fmaf(hx.z, wx.z, a); a = fmaf(hx.w, wx.w, a);
        }
        a += __shfl_xor(a, 1, 64);
        a += __shfl_xor(a, 2, 64);
        a += __shfl_xor(a, 4, 64);
        if (qq == 0) {
          const float y = fmaxf(a + s.bout[f], 0.0f);
          out[((gb + w) * T + t) * F + f] = y;
          unsigned short hb, lb; split_tr(y, hb, lb);
          s.xpad[w][f] = hb;
          s.xpad[w][f + 8] = lb;
        }
      }
      __syncthreads();   // h + next input visible for next gemm
    }
  }
}

} // namespace

extern "C" void kernel_launch(void* const* d_in, const int* in_sizes, int n_in,
                              void* d_out, int out_size, void* d_ws, size_t ws_size,
                              hipStream_t stream) {
  const float* x    = (const float*)d_in[0];
  const float* Wenc = (const float*)d_in[1];
  const float* Uenc = (const float*)d_in[2];
  const float* benc = (const float*)d_in[3];
  const float* Wdec = (const float*)d_in[4];
  const float* Udec = (const float*)d_in[5];
  const float* bdec = (const float*)d_in[6];
  const float* Wout = (const float*)d_in[7];
  const float* bout = (const float*)d_in[8];
  float* out = (float*)d_out;

  const int Bsz = in_sizes[0] / (T * F);  // 2048
  const int nblocks = Bsz / 8;            // 256
  rae_mfma2<<<dim3(nblocks), dim3(NTH), 0, stream>>>(
      x, Wenc, Uenc, benc, Wdec, Udec, bdec, Wout, bout, out);
}

// Round 4
// 1410.927 us; speedup vs baseline: 5.4183x; 1.3692x over previous
//
#include <hip/hip_runtime.h>

// RegressiveAutoEncoder B=2048,T=512,F=8,H=128 — MFMA v4 (gate-interleaved).
// 256 blocks x 512 threads; block owns 8 batch rows, 1024 sequential steps.
// Wave w owns cols w*16..+15 of EACH gate -> all 4 gate values for a cell sit
// in one lane's accs -> in-register cell update, no z LDS round-trip, ONE
// barrier per step. h (bf16) and x/y staging double-buffered by step parity.
// Decoder dense y=relu(h@Wout+b) computed redundantly per-wave via 4 MFMAs
// (Wout_lo in N-cols 8..15, shfl_xor(8) correction); feedback writes idempotent.
// 2-term split: A@B1(hi) + A@B2(lo); h = rtn-bf16; x/y 3-term via k-slots 136..143.

namespace {

typedef __attribute__((ext_vector_type(8))) short bf16x8;
typedef __attribute__((ext_vector_type(4))) float f32x4;

constexpr int T = 512, F = 8, H = 128, G4 = 512, NTH = 512;
constexpr int HS = 136;  // shorts per hb row (272B, b128-aligned)
constexpr int XS = 32;   // shorts per xp row: [hi 0..7 | lo 8..15 | zeros]

struct __align__(16) Smem {
  unsigned short hb[2][16][HS];  // h bf16, A-layout, double-buffered; rows 8..15 stay 0
  unsigned short xp[2][16][XS];  // input (x_t / y_{t-1}) hi|lo, double-buffered
};

__device__ __forceinline__ float rcpf(float v) { return __builtin_amdgcn_rcpf(v); }
__device__ __forceinline__ float sigm(float v) { return rcpf(1.0f + __expf(-v)); }
__device__ __forceinline__ float tanh_(float v) { return 1.0f - 2.0f * rcpf(__expf(2.0f * v) + 1.0f); }

__device__ __forceinline__ unsigned short bf_rtn(float v) {
  unsigned u = __float_as_uint(v);
  return (unsigned short)((u + 0x7FFFu + ((u >> 16) & 1u)) >> 16);
}
__device__ __forceinline__ void split_tr(float v, unsigned short& hi, unsigned short& lo) {
  unsigned u = __float_as_uint(v);
  hi = (unsigned short)(u >> 16);
  lo = bf_rtn(v - __uint_as_float(u & 0xFFFF0000u));
}

__global__ __launch_bounds__(NTH, 2)
void rae_v4(const float* __restrict__ x,
            const float* __restrict__ Wenc, const float* __restrict__ Uenc, const float* __restrict__ benc,
            const float* __restrict__ Wdec, const float* __restrict__ Udec, const float* __restrict__ bdec,
            const float* __restrict__ Wout, const float* __restrict__ boutg,
            float* __restrict__ out)
{
  __shared__ Smem s;
  const int tid = threadIdx.x, lane = tid & 63, w = tid >> 6;
  const int q = lane >> 4, n = lane & 15;
  const long gb = (long)blockIdx.x * 8;

  for (int i = tid; i < 2 * 16 * HS; i += NTH) (&s.hb[0][0][0])[i] = 0;
  for (int i = tid; i < 2 * 16 * XS; i += NTH) (&s.xp[0][0][0])[i] = 0;
  if (tid < 64) {
    unsigned short hv, lv; split_tr(x[(gb + (tid >> 3)) * (long)(T * F) + (tid & 7)], hv, lv);
    s.xp[0][tid >> 3][tid & 7] = hv; s.xp[0][tid >> 3][(tid & 7) + 8] = lv;
  }

  // Wout fragments: N-cols 0..7 = Wout_hi, 8..15 = Wout_lo (corr via shfl_xor 8)
  bf16x8 Bw[4];
#pragma unroll
  for (int kt = 0; kt < 4; ++kt) {
    bf16x8 bw;
#pragma unroll
    for (int j = 0; j < 8; ++j) {
      unsigned short hv, lv; split_tr(Wout[(kt * 32 + q * 8 + j) * F + (n & 7)], hv, lv);
      bw[j] = (short)((n < 8) ? hv : lv);
    }
    Bw[kt] = bw;
  }
  const float boutr = boutg[n & 7];
  float cst[2] = {0.f, 0.f};  // cell state: lane's 2 cells (rows r0, r0+1, col cc)
  __syncthreads();

  bf16x8 A[5];
  {
    bf16x8 zz = {0, 0, 0, 0, 0, 0, 0, 0};
#pragma unroll
    for (int kt = 0; kt < 5; ++kt) A[kt] = zz;  // h_0 = 0
  }

  bf16x8 B1[5][4], B2[5][4];
  float brg[4];

  for (int ph = 0; ph < 2; ++ph) {
    const float* U  = ph ? Udec : Uenc;
    const float* W  = ph ? Wdec : Wenc;
    const float* bi = ph ? bdec : benc;

    // B-fragment preload: gate g tile cols g*128 + w*16 + n; k 0..127=U, 128..143=W(hi|lo-slots)
#pragma unroll
    for (int kt = 0; kt < 5; ++kt)
#pragma unroll
      for (int g = 0; g < 4; ++g) {
        const int col = g * 128 + w * 16 + n;
        bf16x8 b1, b2;
#pragma unroll
        for (int j = 0; j < 8; ++j) {
          unsigned short hv = 0, lv = 0;
          if (kt < 4) {
            split_tr(U[(kt * 32 + q * 8 + j) * G4 + col], hv, lv);
          } else {
            const int kk = q * 8 + j;
            if (kk < 8) split_tr(W[kk * G4 + col], hv, lv);            // x_hi @ (W_hi, W_lo)
            else if (kk < 16) { unsigned short t2; split_tr(W[(kk - 8) * G4 + col], hv, t2); lv = 0; } // x_lo @ W_hi
          }
          b1[j] = (short)hv; b2[j] = (short)lv;
        }
        B1[kt][g] = b1; B2[kt][g] = b2;
      }
#pragma unroll
    for (int g = 0; g < 4; ++g) brg[g] = bi[g * 128 + w * 16 + n];

    if (ph == 1) {  // stage y_{-1} = x[:,T-1,:] into slot 0 (dec iter 0 reads pcur=0)
      if (tid < 64) {
        unsigned short hv, lv;
        split_tr(x[(gb + (tid >> 3)) * (long)(T * F) + (T - 1) * F + (tid & 7)], hv, lv);
        s.xp[0][tid >> 3][tid & 7] = hv; s.xp[0][tid >> 3][(tid & 7) + 8] = lv;
      }
      __syncthreads();
    }

    for (int t = 0; t < T; ++t) {
      const int pcur = t & 1, pnxt = (t + 1) & 1;
      float xnext = 0.f;
      if (ph == 0 && tid < 64 && t + 1 < T)
        xnext = x[(gb + (tid >> 3)) * (long)(T * F) + (t + 1) * F + (tid & 7)];

      A[4] = *(const bf16x8*)&s.xp[pcur][n][q * 8];

      f32x4 acc[4];
#pragma unroll
      for (int g = 0; g < 4; ++g) acc[g] = f32x4{brg[g], brg[g], brg[g], brg[g]};
#pragma unroll
      for (int kt = 0; kt < 5; ++kt)
#pragma unroll
        for (int g = 0; g < 4; ++g)
          acc[g] = __builtin_amdgcn_mfma_f32_16x16x32_bf16(A[kt], B1[kt][g], acc[g], 0, 0, 0);
#pragma unroll
      for (int kt = 0; kt < 5; ++kt)
#pragma unroll
        for (int g = 0; g < 4; ++g)
          acc[g] = __builtin_amdgcn_mfma_f32_16x16x32_bf16(A[kt], B2[kt][g], acc[g], 0, 0, 0);

      // ---- in-register cell update; lanes>=32 take p=2,3 via shfl ----
      float zA[4], zB[4];
#pragma unroll
      for (int g = 0; g < 4; ++g) {
        float a2 = __shfl_xor(acc[g][2], 32, 64);
        float a3 = __shfl_xor(acc[g][3], 32, 64);
        zA[g] = (lane < 32) ? acc[g][0] : a2;
        zB[g] = (lane < 32) ? acc[g][1] : a3;
      }
      const int r0 = ((lane & 31) >> 4) * 4 + ((lane < 32) ? 0 : 2);
      const int cc = w * 16 + n;
      cst[0] = sigm(zA[1]) * cst[0] + sigm(zA[0]) * tanh_(zA[2]);
      cst[1] = sigm(zB[1]) * cst[1] + sigm(zB[0]) * tanh_(zB[2]);
      const float h0 = sigm(zA[3]) * tanh_(cst[0]);
      const float h1 = sigm(zB[3]) * tanh_(cst[1]);
      s.hb[pnxt][r0][cc]     = bf_rtn(h0);
      s.hb[pnxt][r0 + 1][cc] = bf_rtn(h1);

      if (ph == 0 && tid < 64 && t + 1 < T) {
        unsigned short hv, lv; split_tr(xnext, hv, lv);
        s.xp[pnxt][tid >> 3][tid & 7] = hv; s.xp[pnxt][tid >> 3][(tid & 7) + 8] = lv;
      }
      __syncthreads();   // the ONLY barrier per step

      // h fragments for next iter (and for dense below)
#pragma unroll
      for (int kt = 0; kt < 4; ++kt)
        A[kt] = *(const bf16x8*)&s.hb[pnxt][n][kt * 32 + q * 8];

      if (ph == 1) {
        // dense y_t = relu(h_t @ Wout + b), redundant per wave (4 MFMAs)
        f32x4 ay = {0.f, 0.f, 0.f, 0.f};
#pragma unroll
        for (int kt = 0; kt < 4; ++kt)
          ay = __builtin_amdgcn_mfma_f32_16x16x32_bf16(A[kt], Bw[kt], ay, 0, 0, 0);
        float y[4];
#pragma unroll
        for (int p = 0; p < 4; ++p) {
          float corr = __shfl_xor(ay[p], 8, 64);   // h@Wout_lo from col n+8
          y[p] = fmaxf(ay[p] + corr + boutr, 0.f);
        }
        if (q < 2 && n < 8) {                       // valid rows q*4+p, col f=n
          const int rr = q * 4;
          if (w == 0) {
#pragma unroll
            for (int p = 0; p < 4; ++p)
              out[((gb + rr + p) * T + t) * F + n] = y[p];
          }
#pragma unroll
          for (int p = 0; p < 4; ++p) {             // idempotent feedback staging
            unsigned short hv, lv; split_tr(y[p], hv, lv);
            s.xp[pnxt][rr + p][n]     = hv;
            s.xp[pnxt][rr + p][n + 8] = lv;
          }
        }
      }
    }
  }
}

} // namespace

extern "C" void kernel_launch(void* const* d_in, const int* in_sizes, int n_in,
                              void* d_out, int out_size, void* d_ws, size_t ws_size,
                              hipStream_t stream) {
  const float* x    = (const float*)d_in[0];
  const float* Wenc = (const float*)d_in[1];
  const float* Uenc = (const float*)d_in[2];
  const float* benc = (const float*)d_in[3];
  const float* Wdec = (const float*)d_in[4];
  const float* Udec = (const float*)d_in[5];
  const float* bdec = (const float*)d_in[6];
  const float* Wout = (const float*)d_in[7];
  const float* bout = (const float*)d_in[8];
  float* out = (float*)d_out;

  const int Bsz = in_sizes[0] / (T * F);  // 2048
  const int nblocks = Bsz / 8;            // 256
  rae_v4<<<dim3(nblocks), dim3(NTH), 0, stream>>>(
      x, Wenc, Uenc, benc, Wdec, Udec, bdec, Wout, bout, out);
}

// Round 5
// 1376.546 us; speedup vs baseline: 5.5537x; 1.0250x over previous
//
#include <hip/hip_runtime.h>

// RegressiveAutoEncoder B=2048,T=512,F=8,H=128 — MFMA v5 (hi/lo-in-rows).
// 256 blocks x 512 threads; block owns 8 batch rows, 1024 sequential steps.
// SINGLE MFMA pass: A rows 0..7 = h_hi (batch rows), rows 8..15 = h_lo.
// C rows r / r+8 then hold h_hi@U + h_lo@U; shfl_xor(32)+add fuses them ->
// full-precision h@U_hi with HALF the MFMAs of v4 (20/wave/step).
// U = rtn-bf16 single term; x/y = 3-term via kt=4 tile: rows0-7 [x_hi|0],
// rows8-15 [x_lo|x_hi] against B slots [W_hi|W_lo]. Bias init at 0.5x (rows
// counted twice). One barrier/step; h,x double-buffered by parity; decoder
// dense redundant per wave (Wout_lo in N-cols 8..15; shfl8 + shfl32 fold).

namespace {

typedef __attribute__((ext_vector_type(8))) short bf16x8;
typedef __attribute__((ext_vector_type(4))) float f32x4;

constexpr int T = 512, F = 8, H = 128, G4 = 512, NTH = 512;
constexpr int HS = 136;  // shorts per hb row (272B, b128-aligned)
constexpr int XS = 32;   // shorts per xp row

struct __align__(16) Smem {
  unsigned short hb[2][16][HS];  // rows 0..7 h_hi, rows 8..15 h_lo; dbuf by parity
  unsigned short xp[2][16][XS];  // rows 0..7 [x_hi|0..], rows 8..15 [x_lo|x_hi]
};

__device__ __forceinline__ float rcpf(float v) { return __builtin_amdgcn_rcpf(v); }
__device__ __forceinline__ float sigm(float v) { return rcpf(1.0f + __expf(-v)); }
__device__ __forceinline__ float tanh_(float v) { return 1.0f - 2.0f * rcpf(__expf(2.0f * v) + 1.0f); }

__device__ __forceinline__ unsigned short bf_rtn(float v) {
  unsigned u = __float_as_uint(v);
  return (unsigned short)((u + 0x7FFFu + ((u >> 16) & 1u)) >> 16);
}
__device__ __forceinline__ void split_tr(float v, unsigned short& hi, unsigned short& lo) {
  unsigned u = __float_as_uint(v);
  hi = (unsigned short)(u >> 16);
  lo = bf_rtn(v - __uint_as_float(u & 0xFFFF0000u));
}

__global__ __launch_bounds__(NTH, 2)
void rae_v5(const float* __restrict__ x,
            const float* __restrict__ Wenc, const float* __restrict__ Uenc, const float* __restrict__ benc,
            const float* __restrict__ Wdec, const float* __restrict__ Udec, const float* __restrict__ bdec,
            const float* __restrict__ Wout, const float* __restrict__ boutg,
            float* __restrict__ out)
{
  __shared__ Smem s;
  const int tid = threadIdx.x, lane = tid & 63, w = tid >> 6;
  const int q = lane >> 4, n = lane & 15;
  const long gb = (long)blockIdx.x * 8;

  for (int i = tid; i < 2 * 16 * HS; i += NTH) (&s.hb[0][0][0])[i] = 0;
  for (int i = tid; i < 2 * 16 * XS; i += NTH) (&s.xp[0][0][0])[i] = 0;
  if (tid < 64) {   // stage x_0: r=tid>>3, f=tid&7
    unsigned short hv, lv; split_tr(x[(gb + (tid >> 3)) * (long)(T * F) + (tid & 7)], hv, lv);
    s.xp[0][tid >> 3][tid & 7] = hv;
    s.xp[0][(tid >> 3) + 8][tid & 7] = lv;
    s.xp[0][(tid >> 3) + 8][(tid & 7) + 8] = hv;
  }

  // Wout fragments: N-cols 0..7 = Wout_hi, 8..15 = Wout_lo
  bf16x8 Bw[4];
#pragma unroll
  for (int kt = 0; kt < 4; ++kt) {
    bf16x8 bw;
#pragma unroll
    for (int j = 0; j < 8; ++j) {
      unsigned short hv, lv; split_tr(Wout[(kt * 32 + q * 8 + j) * F + (n & 7)], hv, lv);
      bw[j] = (short)((n < 8) ? hv : lv);
    }
    Bw[kt] = bw;
  }
  const float boutr = boutg[n & 7];
  float cst[2] = {0.f, 0.f};
  __syncthreads();

  bf16x8 A[5];
  {
    bf16x8 zz = {0, 0, 0, 0, 0, 0, 0, 0};
#pragma unroll
    for (int kt = 0; kt < 5; ++kt) A[kt] = zz;
  }

  bf16x8 B1[5][4];
  float brg2[4];

  for (int ph = 0; ph < 2; ++ph) {
    const float* U  = ph ? Udec : Uenc;
    const float* W  = ph ? Wdec : Wenc;
    const float* bi = ph ? bdec : benc;

    // B preload: kt<4 = rtn-bf16(U); kt=4: kk<8 -> W_hi(trunc), kk>=8 -> W_lo
#pragma unroll
    for (int kt = 0; kt < 5; ++kt)
#pragma unroll
      for (int g = 0; g < 4; ++g) {
        const int col = g * 128 + w * 16 + n;
        bf16x8 b1;
#pragma unroll
        for (int j = 0; j < 8; ++j) {
          unsigned short v = 0;
          if (kt < 4) {
            v = bf_rtn(U[(kt * 32 + q * 8 + j) * G4 + col]);
          } else {
            const int kk = q * 8 + j;
            unsigned short hv, lv;
            if (kk < 8) { split_tr(W[kk * G4 + col], hv, lv); v = hv; }
            else        { split_tr(W[(kk - 8) * G4 + col], hv, lv); v = lv; }
          }
          b1[j] = (short)v;
        }
        B1[kt][g] = b1;
      }
#pragma unroll
    for (int g = 0; g < 4; ++g) brg2[g] = 0.5f * bi[g * 128 + w * 16 + n];

    if (ph == 1) {  // stage y_{-1} = x[:,T-1,:] into parity slot 0
      if (tid < 64) {
        unsigned short hv, lv;
        split_tr(x[(gb + (tid >> 3)) * (long)(T * F) + (T - 1) * F + (tid & 7)], hv, lv);
        s.xp[0][tid >> 3][tid & 7] = hv;
        s.xp[0][(tid >> 3) + 8][tid & 7] = lv;
        s.xp[0][(tid >> 3) + 8][(tid & 7) + 8] = hv;
      }
      __syncthreads();
    }

    for (int t = 0; t < T; ++t) {
      const int pcur = t & 1, pnxt = (t + 1) & 1;
      float xnext = 0.f;
      if (ph == 0 && tid < 64 && t + 1 < T)
        xnext = x[(gb + (tid >> 3)) * (long)(T * F) + (t + 1) * F + (tid & 7)];

      A[4] = *(const bf16x8*)&s.xp[pcur][n][q * 8];

      // ---- single MFMA pass: 5 ksteps x 4 gates ----
      f32x4 acc[4];
#pragma unroll
      for (int g = 0; g < 4; ++g) acc[g] = f32x4{brg2[g], brg2[g], brg2[g], brg2[g]};
#pragma unroll
      for (int kt = 0; kt < 5; ++kt)
#pragma unroll
        for (int g = 0; g < 4; ++g)
          acc[g] = __builtin_amdgcn_mfma_f32_16x16x32_bf16(A[kt], B1[kt][g], acc[g], 0, 0, 0);

      // ---- fuse hi/lo rows: rows r (lanes<32) + r+8 (lanes>=32) ----
#pragma unroll
      for (int g = 0; g < 4; ++g)
#pragma unroll
        for (int p = 0; p < 4; ++p)
          acc[g][p] += __shfl_xor(acc[g][p], 32, 64);

      float zA[4], zB[4];
#pragma unroll
      for (int g = 0; g < 4; ++g) {
        zA[g] = (lane < 32) ? acc[g][0] : acc[g][2];
        zB[g] = (lane < 32) ? acc[g][1] : acc[g][3];
      }
      const int r0 = ((lane & 31) >> 4) * 4 + ((lane < 32) ? 0 : 2);
      const int cc = w * 16 + n;
      cst[0] = sigm(zA[1]) * cst[0] + sigm(zA[0]) * tanh_(zA[2]);
      cst[1] = sigm(zB[1]) * cst[1] + sigm(zB[0]) * tanh_(zB[2]);
      const float h0 = sigm(zA[3]) * tanh_(cst[0]);
      const float h1 = sigm(zB[3]) * tanh_(cst[1]);
      {
        unsigned short hv0, lv0, hv1, lv1;
        split_tr(h0, hv0, lv0); split_tr(h1, hv1, lv1);
        s.hb[pnxt][r0][cc]     = hv0;  s.hb[pnxt][r0 + 8][cc] = lv0;
        s.hb[pnxt][r0 + 1][cc] = hv1;  s.hb[pnxt][r0 + 9][cc] = lv1;
      }

      if (ph == 0 && tid < 64 && t + 1 < T) {
        unsigned short hv, lv; split_tr(xnext, hv, lv);
        s.xp[pnxt][tid >> 3][tid & 7] = hv;
        s.xp[pnxt][(tid >> 3) + 8][tid & 7] = lv;
        s.xp[pnxt][(tid >> 3) + 8][(tid & 7) + 8] = hv;
      }
      __syncthreads();   // the only barrier per step

      // h fragments for next iter / dense (rows 0..15 incl. lo-rows)
#pragma unroll
      for (int kt = 0; kt < 4; ++kt)
        A[kt] = *(const bf16x8*)&s.hb[pnxt][n][kt * 32 + q * 8];

      if (ph == 1) {
        // dense y = relu(h@Wout + b), redundant per wave
        f32x4 ay = {0.f, 0.f, 0.f, 0.f};
#pragma unroll
        for (int kt = 0; kt < 4; ++kt)
          ay = __builtin_amdgcn_mfma_f32_16x16x32_bf16(A[kt], Bw[kt], ay, 0, 0, 0);
        float y[4];
#pragma unroll
        for (int p = 0; p < 4; ++p) {
          float s8 = ay[p] + __shfl_xor(ay[p], 8, 64);    // + h@Wout_lo
          float s32 = s8 + __shfl_xor(s8, 32, 64);        // + h_lo@Wout
          y[p] = fmaxf(s32 + boutr, 0.f);
        }
        if (q < 2 && n < 8) {                             // rows q*4+p, col f=n
          const int rr = q * 4;
          if (w == 0) {
#pragma unroll
            for (int p = 0; p < 4; ++p)
              out[((gb + rr + p) * T + t) * F + n] = y[p];
          }
#pragma unroll
          for (int p = 0; p < 4; ++p) {                   // idempotent feedback
            unsigned short hv, lv; split_tr(y[p], hv, lv);
            s.xp[pnxt][rr + p][n]         = hv;
            s.xp[pnxt][rr + p + 8][n]     = lv;
            s.xp[pnxt][rr + p + 8][n + 8] = hv;
          }
        }
      }
    }
  }
}

} // namespace

extern "C" void kernel_launch(void* const* d_in, const int* in_sizes, int n_in,
                              void* d_out, int out_size, void* d_ws, size_t ws_size,
                              hipStream_t stream) {
  const float* x    = (const float*)d_in[0];
  const float* Wenc = (const float*)d_in[1];
  const float* Uenc = (const float*)d_in[2];
  const float* benc = (const float*)d_in[3];
  const float* Wdec = (const float*)d_in[4];
  const float* Udec = (const float*)d_in[5];
  const float* bdec = (const float*)d_in[6];
  const float* Wout = (const float*)d_in[7];
  const float* bout = (const float*)d_in[8];
  float* out = (float*)d_out;

  const int Bsz = in_sizes[0] / (T * F);  // 2048
  const int nblocks = Bsz / 8;            // 256
  rae_v5<<<dim3(nblocks), dim3(NTH), 0, stream>>>(
      x, Wenc, Uenc, benc, Wdec, Udec, bdec, Wout, bout, out);
}